// Round 1
// 830.553 us; speedup vs baseline: 1.0854x; 1.0854x over previous
//
#include <hip/hip_runtime.h>
#include <hip/hip_bf16.h>
#include <math.h>

// TriAttStart: L=512, Z=128, H=4, C=32.
// Pipeline: prep -> proj(LN fused) -> att(split-K) -> softmax -> o(gate fused) -> final.
// All GEMMs: mfma_f32_16x16x32_bf16, bf16 operands / fp32 accumulate.
// R1: k_proj rewritten — one block per mtile loops all 5 ntiles (z read once, LN once),
//     B fragments straight from L2-resident Wt (no Bs LDS -> 4 blocks/CU),
//     swapped-operand MFMA so epilogue stores are packed ushort4/float4.

#define LL 512
#define ZD 128
#define NROWS (LL*LL)
#define ATT_SCALE (1.0f/128.0f)   // (1/sqrt(32))/sqrt(512)
#define NSPLIT 8

typedef __attribute__((ext_vector_type(4))) float f32x4;
typedef __attribute__((ext_vector_type(8))) short short8;
typedef __attribute__((ext_vector_type(8))) unsigned short u16x8;

__device__ __forceinline__ unsigned short f2bf(float f){
  union { float f; unsigned u; } v; v.f = f;
  unsigned r = (v.u + 0x7FFFu + ((v.u >> 16) & 1u)) >> 16;
  return (unsigned short)r;
}
__device__ __forceinline__ float bf2f(unsigned short h){
  union { float f; unsigned u; } v; v.u = ((unsigned)h) << 16;
  return v.f;
}

// ---------------------------------------------------------------- prep
// Wt[n][k] bf16, n: 0-127 qw | 128-255 kw | 256-383 vw | 384-511 gw | 512-515 bw.
// Ot[d][k] = ow[k][d]. biasv[n] packed biases.
__global__ void k_prep(const float* __restrict__ qw, const float* __restrict__ kw,
                       const float* __restrict__ vw, const float* __restrict__ gw,
                       const float* __restrict__ bw,
                       const float* __restrict__ qb, const float* __restrict__ kb,
                       const float* __restrict__ vb, const float* __restrict__ gb,
                       const float* __restrict__ bb,
                       const float* __restrict__ ow,
                       unsigned short* __restrict__ Wt, unsigned short* __restrict__ Ot,
                       float* __restrict__ biasv){
  int n = blockIdx.x;
  int k = threadIdx.x;
  if (n < 516){
    float v;
    if (n < 128)      v = qw[k*128 + n];
    else if (n < 256) v = kw[k*128 + (n-128)];
    else if (n < 384) v = vw[k*128 + (n-256)];
    else if (n < 512) v = gw[k*128 + (n-384)];
    else              v = bw[k*4   + (n-512)];
    Wt[n*ZD + k] = f2bf(v);
    if (k == 0){
      float bvv;
      if (n < 128)      bvv = qb[n];
      else if (n < 256) bvv = kb[n-128];
      else if (n < 384) bvv = vb[n-256];
      else if (n < 512) bvv = gb[n-384];
      else              bvv = bb[n-512];
      biasv[n] = bvv;
    }
  } else {
    int d = n - 516;
    Ot[d*ZD + k] = f2bf(ow[k*ZD + d]);
  }
}

// ---------------------------------------------------------------- proj (LN fused)
// grid 2048 mtiles. Each block: LN its 128x128 z tile once into As, then loop the
// 5 ntiles (q|k|v|g|b) with B fragments loaded directly from L2-resident Wt.
// MFMA operands SWAPPED (mfma(b,a,acc)) => lane regs span 4 consecutive out-cols:
// packed ushort4 stores for proj, float4 for biasz.
__launch_bounds__(256, 4)
__global__ void k_proj(const float* __restrict__ z,
                       const float* __restrict__ ln_g, const float* __restrict__ ln_b,
                       const unsigned short* __restrict__ Wt,
                       const float* __restrict__ biasv,
                       unsigned short* __restrict__ proj,
                       float* __restrict__ biasz){
  const int P = 136;
  __shared__ unsigned short As[128*136];
  __shared__ float lng[128], lnb[128];
  __shared__ float lbias[640];
  int t = threadIdx.x;
  long mbase = (long)blockIdx.x * 128;
  if (t < 128){ lng[t] = ln_g[t]; lnb[t] = ln_b[t]; }
  if (t < 160) *(float4*)&lbias[t*4] = *(const float4*)&biasv[t*4];
  {
    int row = t >> 1, half = t & 1;
    const float4* zr = (const float4*)(z + (mbase + row)*ZD + half*64);
    float s1 = 0.f, s2 = 0.f;
    for (int i = 0; i < 16; i++){
      float4 v = zr[i];
      s1 += v.x + v.y + v.z + v.w;
      s2 += v.x*v.x + v.y*v.y + v.z*v.z + v.w*v.w;
    }
    s1 += __shfl_xor(s1, 1);
    s2 += __shfl_xor(s2, 1);
    float mu = s1 * (1.f/128.f);
    float rs = rsqrtf(s2*(1.f/128.f) - mu*mu + 1e-5f);
    __syncthreads();   // lng/lnb/lbias visible
    for (int i = 0; i < 16; i++){
      float4 v = zr[i];      // re-read; L1/L2-hot
      int c0 = half*64 + i*4;
      ushort4 pk;
      pk.x = f2bf((v.x - mu)*rs*lng[c0+0] + lnb[c0+0]);
      pk.y = f2bf((v.y - mu)*rs*lng[c0+1] + lnb[c0+1]);
      pk.z = f2bf((v.z - mu)*rs*lng[c0+2] + lnb[c0+2]);
      pk.w = f2bf((v.w - mu)*rs*lng[c0+3] + lnb[c0+3]);
      *(ushort4*)&As[row*P + c0] = pk;
    }
  }
  __syncthreads();
  int w = t >> 6, tl = t & 63;
  int m0 = (w & 1)*64, n0 = (w >> 1)*64;
  int lr = tl & 15, quad = tl >> 4;
  for (int nt = 0; nt < 5; nt++){
    f32x4 acc[4][4];
    for (int i=0;i<4;i++) for (int j=0;j<4;j++) acc[i][j] = f32x4{0.f,0.f,0.f,0.f};
    for (int kk = 0; kk < 4; kk++){
      short8 a[4], bq[4];
      for (int i=0;i<4;i++) a[i] = *(const short8*)&As[(m0 + i*16 + lr)*P + kk*32 + quad*8];
      const unsigned short* wp = Wt + ((long)nt*128 + n0 + lr)*ZD + kk*32 + quad*8;
      for (int j=0;j<4;j++) bq[j] = *(const short8*)(wp + (long)j*16*ZD);
      for (int i=0;i<4;i++) for (int j=0;j<4;j++)
        acc[i][j] = __builtin_amdgcn_mfma_f32_16x16x32_bf16(bq[j], a[i], acc[i][j], 0,0,0);
    }
    // swapped layout: lane holds rows (m0+i*16+lr), 4 consecutive cols (n0+j*16+quad*4 + 0..3)
    if (nt < 4){
      for (int j=0;j<4;j++){
        int nc0 = n0 + j*16 + quad*4;
        float4 bd = *(const float4*)&lbias[nt*128 + nc0];
        for (int i=0;i<4;i++){
          long grow = mbase + m0 + i*16 + lr;
          ushort4 pk;
          pk.x = f2bf(acc[i][j][0] + bd.x);
          pk.y = f2bf(acc[i][j][1] + bd.y);
          pk.z = f2bf(acc[i][j][2] + bd.z);
          pk.w = f2bf(acc[i][j][3] + bd.w);
          *(ushort4*)&proj[grow*512 + nt*128 + nc0] = pk;
        }
      }
    } else if (n0 == 0 && quad == 0){
      float4 bd = *(const float4*)&lbias[512];
      for (int i=0;i<4;i++){
        long grow = mbase + m0 + i*16 + lr;
        float4 o;
        o.x = acc[i][0][0] + bd.x;
        o.y = acc[i][0][1] + bd.y;
        o.z = acc[i][0][2] + bd.z;
        o.w = acc[i][0][3] + bd.w;
        *(float4*)&biasz[grow*4] = o;
      }
    }
  }
}

// ---------------------------------------------------------------- att (split-K)
// att_part[s][h][l][k'] = sum over b in split s of q[b,l,h,:].k[b,k',h,:]
// grid (kt 4, lt 4, split*4+h 32). K-loop: 64 b-iters, BK = 32 (the c dim).
__launch_bounds__(256, 2)
__global__ void k_att(const unsigned short* __restrict__ proj,
                      float* __restrict__ partial){
  const int P = 40;
  __shared__ unsigned short As[128*40];
  __shared__ unsigned short Bs[128*40];
  int t = threadIdx.x;
  int ktb = blockIdx.x * 128, ltb = blockIdx.y * 128;
  int split = blockIdx.z >> 2, h = blockIdx.z & 3;
  int w = t >> 6, tl = t & 63;
  int m0 = (w & 1)*64, n0 = (w >> 1)*64;
  int lr = tl & 15, quad = tl >> 4;
  int srow = t >> 1, shalf = t & 1;
  f32x4 acc[4][4];
  for (int i=0;i<4;i++) for (int j=0;j<4;j++) acc[i][j] = f32x4{0.f,0.f,0.f,0.f};
  for (int it = 0; it < 64; it++){
    int b = split*64 + it;
    long abase = ((long)b*LL + ltb + srow)*512 +       h*32 + shalf*16;
    long bbase = ((long)b*LL + ktb + srow)*512 + 128 + h*32 + shalf*16;
    u16x8 av0 = *(const u16x8*)&proj[abase];
    u16x8 av1 = *(const u16x8*)&proj[abase + 8];
    u16x8 bv0 = *(const u16x8*)&proj[bbase];
    u16x8 bv1 = *(const u16x8*)&proj[bbase + 8];
    __syncthreads();
    *(u16x8*)&As[srow*P + shalf*16]     = av0;
    *(u16x8*)&As[srow*P + shalf*16 + 8] = av1;
    *(u16x8*)&Bs[srow*P + shalf*16]     = bv0;
    *(u16x8*)&Bs[srow*P + shalf*16 + 8] = bv1;
    __syncthreads();
    short8 a[4], bq[4];
    for (int i=0;i<4;i++) a[i]  = *(const short8*)&As[(m0 + i*16 + lr)*P + quad*8];
    for (int i=0;i<4;i++) bq[i] = *(const short8*)&Bs[(n0 + i*16 + lr)*P + quad*8];
    for (int i=0;i<4;i++) for (int j=0;j<4;j++)
      acc[i][j] = __builtin_amdgcn_mfma_f32_16x16x32_bf16(a[i], bq[j], acc[i][j], 0,0,0);
  }
  long obase = (((long)(split*4 + h)*LL) + ltb)*512 + ktb;
  for (int i=0;i<4;i++) for (int j=0;j<4;j++){
    int ncol = n0 + j*16 + lr;
    for (int r=0;r<4;r++){
      int mrow = m0 + i*16 + quad*4 + r;
      partial[obase + (long)mrow*512 + ncol] = acc[i][j][r];
    }
  }
}

// ---------------------------------------------------------------- softmax
// grid 2048 = (h,l). sum splits, scale, +bias, softmax over k (512), write bf16.
__global__ void k_soft(const float* __restrict__ partial,
                       const float* __restrict__ biasz,
                       unsigned short* __restrict__ attb){
  int bx = blockIdx.x;
  int h = bx >> 9, l = bx & 511;
  int t = threadIdx.x;
  int k1 = t, k2 = t + 256;
  float v1 = 0.f, v2 = 0.f;
  for (int s = 0; s < NSPLIT; s++){
    long base = (((long)(s*4 + h)*LL) + l)*512;
    v1 += partial[base + k1];
    v2 += partial[base + k2];
  }
  v1 = v1*ATT_SCALE + biasz[((long)l*512 + k1)*4 + h];
  v2 = v2*ATT_SCALE + biasz[((long)l*512 + k2)*4 + h];
  __shared__ float red[4];
  int w = t >> 6, tl = t & 63;
  float mx = fmaxf(v1, v2);
  for (int o = 32; o > 0; o >>= 1) mx = fmaxf(mx, __shfl_xor(mx, o));
  if (tl == 0) red[w] = mx;
  __syncthreads();
  mx = fmaxf(fmaxf(red[0], red[1]), fmaxf(red[2], red[3]));
  __syncthreads();
  float e1 = __expf(v1 - mx), e2 = __expf(v2 - mx);
  float sm = e1 + e2;
  for (int o = 32; o > 0; o >>= 1) sm += __shfl_xor(sm, o);
  if (tl == 0) red[w] = sm;
  __syncthreads();
  sm = red[0] + red[1] + red[2] + red[3];
  float inv = 1.f / sm;
  long ob = ((long)h*LL + l)*512;
  attb[ob + k1] = f2bf(e1*inv);
  attb[ob + k2] = f2bf(e2*inv);
}

// ---------------------------------------------------------------- o GEMM + gate
// grid (lt 4, b 512). wave w = head w: [128 l] x [32 c], K-loop over k' (BK=32).
// B tile (v) transposed k,c -> c,k in LDS. Epilogue: x = sigmoid(g) * o -> bf16.
__launch_bounds__(256, 2)
__global__ void k_o(const unsigned short* __restrict__ attb,
                    const unsigned short* __restrict__ proj,
                    unsigned short* __restrict__ xbuf){
  const int P = 40;
  __shared__ unsigned short As[4*128*40];
  __shared__ unsigned short Bs[4*32*40];
  int t = threadIdx.x;
  int ltb = blockIdx.x * 128;
  int b   = blockIdx.y;
  int w = t >> 6, tl = t & 63;
  int lr = tl & 15, quad = tl >> 4;
  f32x4 acc[8][2];
  for (int i=0;i<8;i++) for (int j=0;j<2;j++) acc[i][j] = f32x4{0.f,0.f,0.f,0.f};
  for (int it = 0; it < 16; it++){
    int kb = it*32;
    long a0 = (((long)w*LL) + ltb + tl)*512 + kb;
    long a1 = a0 + 64L*512;
    u16x8 r0[4], r1[4];
    for (int i=0;i<4;i++) r0[i] = *(const u16x8*)&attb[a0 + i*8];
    for (int i=0;i<4;i++) r1[i] = *(const u16x8*)&attb[a1 + i*8];
    int kp = tl >> 1, hc2 = tl & 1;
    long vbs = ((long)b*LL + kb + kp)*512 + 256 + w*32 + hc2*16;
    u16x8 v0 = *(const u16x8*)&proj[vbs];
    u16x8 v1 = *(const u16x8*)&proj[vbs + 8];
    __syncthreads();
    for (int i=0;i<4;i++) *(u16x8*)&As[(w*128 + tl)*P + i*8]      = r0[i];
    for (int i=0;i<4;i++) *(u16x8*)&As[(w*128 + tl + 64)*P + i*8] = r1[i];
    for (int j=0;j<8;j++){
      Bs[(w*32 + hc2*16 + j    )*P + kp] = v0[j];
      Bs[(w*32 + hc2*16 + 8 + j)*P + kp] = v1[j];
    }
    __syncthreads();
    short8 a[8], bq[2];
    for (int i=0;i<8;i++) a[i]  = *(const short8*)&As[(w*128 + i*16 + lr)*P + quad*8];
    for (int j=0;j<2;j++) bq[j] = *(const short8*)&Bs[(w*32  + j*16 + lr)*P + quad*8];
    for (int i=0;i<8;i++) for (int j=0;j<2;j++)
      acc[i][j] = __builtin_amdgcn_mfma_f32_16x16x32_bf16(a[i], bq[j], acc[i][j], 0,0,0);
  }
  for (int i=0;i<8;i++) for (int j=0;j<2;j++) for (int r=0;r<4;r++){
    int l = i*16 + quad*4 + r;
    int c = j*16 + lr;
    long grow = (long)b*LL + ltb + l;
    float gv = bf2f(proj[grow*512 + 384 + w*32 + c]);
    float sg = 1.f / (1.f + __expf(-gv));
    xbuf[grow*128 + w*32 + c] = f2bf(acc[i][j][r] * sg);
  }
}

// ---------------------------------------------------------------- final projection
// out[row][d] = x[row][:] @ ow + ob, fp32 out. grid 2048 mtiles, K=128 one-shot.
__launch_bounds__(256, 2)
__global__ void k_fin(const unsigned short* __restrict__ xbuf,
                      const unsigned short* __restrict__ Ot,
                      const float* __restrict__ ob,
                      float* __restrict__ out){
  const int P = 136;
  __shared__ unsigned short As[128*136];
  __shared__ unsigned short Bs[128*136];
  int t = threadIdx.x;
  long mbase = (long)blockIdx.x * 128;
  {
    int row = t >> 1, half = t & 1;
    const u16x8* src = (const u16x8*)(xbuf + (mbase + row)*128 + half*64);
    u16x8* dst = (u16x8*)&As[row*P + half*64];
    for (int i=0;i<8;i++) dst[i] = src[i];
    const u16x8* wsrc = (const u16x8*)(Ot + row*128 + half*64);
    u16x8* wdst = (u16x8*)&Bs[row*P + half*64];
    for (int i=0;i<8;i++) wdst[i] = wsrc[i];
  }
  __syncthreads();
  int w = t >> 6, tl = t & 63;
  int m0 = (w & 1)*64, n0 = (w >> 1)*64;
  int lr = tl & 15, quad = tl >> 4;
  f32x4 acc[4][4];
  for (int i=0;i<4;i++) for (int j=0;j<4;j++) acc[i][j] = f32x4{0.f,0.f,0.f,0.f};
  for (int kk = 0; kk < 4; kk++){
    short8 a[4], bq[4];
    for (int i=0;i<4;i++) a[i]  = *(const short8*)&As[(m0 + i*16 + lr)*P + kk*32 + quad*8];
    for (int i=0;i<4;i++) bq[i] = *(const short8*)&Bs[(n0 + i*16 + lr)*P + kk*32 + quad*8];
    for (int i=0;i<4;i++) for (int j=0;j<4;j++)
      acc[i][j] = __builtin_amdgcn_mfma_f32_16x16x32_bf16(a[i], bq[j], acc[i][j], 0,0,0);
  }
  for (int i=0;i<4;i++) for (int j=0;j<4;j++){
    int ncol = n0 + j*16 + lr;
    float bv = ob[ncol];
    for (int r=0;r<4;r++){
      int mrow = m0 + i*16 + quad*4 + r;
      out[(mbase + mrow)*128 + ncol] = acc[i][j][r] + bv;
    }
  }
}

// ---------------------------------------------------------------- launch
extern "C" void kernel_launch(void* const* d_in, const int* in_sizes, int n_in,
                              void* d_out, int out_size, void* d_ws, size_t ws_size,
                              hipStream_t stream){
  (void)in_sizes; (void)n_in; (void)out_size; (void)ws_size;
  const float* z    = (const float*)d_in[0];
  const float* ln_g = (const float*)d_in[1];
  const float* ln_b = (const float*)d_in[2];
  const float* qw   = (const float*)d_in[3];
  const float* qb   = (const float*)d_in[4];
  const float* kw   = (const float*)d_in[5];
  const float* kb   = (const float*)d_in[6];
  const float* vw   = (const float*)d_in[7];
  const float* vb   = (const float*)d_in[8];
  const float* bw   = (const float*)d_in[9];
  const float* bb   = (const float*)d_in[10];
  const float* gw   = (const float*)d_in[11];
  const float* gb   = (const float*)d_in[12];
  const float* ow   = (const float*)d_in[13];
  const float* ob   = (const float*)d_in[14];
  float* out = (float*)d_out;

  // ws layout (~323 MB):
  //   [0,       163840)  Wt   640x128 bf16 (rows 516.. left as poison; never stored from)
  //   [163840,  196608)  Ot   128x128 bf16
  //   [196608,  199168)  biasv 640 fp32 (516 used)
  //   [262144,  +256MB)  proj 262144x512 bf16 (q|k|v|g)
  //   [Xreg,    +64MB )  union: {partial 32MB fp32 ; biasz 4MB fp32} then xbuf 64MB bf16
  //   [Xreg+64MB,+2MB )  attb 4x512x512 bf16
  char* wsp = (char*)d_ws;
  unsigned short* Wt    = (unsigned short*)(wsp);
  unsigned short* Ot    = (unsigned short*)(wsp + 163840);
  float*          biasv = (float*)(wsp + 196608);
  unsigned short* proj  = (unsigned short*)(wsp + 262144);
  char* xreg = wsp + 262144 + 268435456L;
  float*          partial = (float*)xreg;
  float*          biasz   = (float*)(xreg + 33554432L);
  unsigned short* xbuf    = (unsigned short*)xreg;
  unsigned short* attb    = (unsigned short*)(xreg + 67108864L);

  k_prep<<<644, 128, 0, stream>>>(qw,kw,vw,gw,bw,qb,kb,vb,gb,bb,ow,Wt,Ot,biasv);
  k_proj<<<2048, 256, 0, stream>>>(z, ln_g, ln_b, Wt, biasv, proj, biasz);
  k_att<<<dim3(4,4,32), 256, 0, stream>>>(proj, partial);
  k_soft<<<2048, 256, 0, stream>>>(partial, biasz, attb);
  k_o<<<dim3(4,512), 256, 0, stream>>>(attb, proj, xbuf);
  k_fin<<<2048, 256, 0, stream>>>(xbuf, Ot, ob, out);
}

// Round 2
// 667.212 us; speedup vs baseline: 1.3511x; 1.2448x over previous
//
#include <hip/hip_runtime.h>
#include <hip/hip_bf16.h>
#include <math.h>

// TriAttStart: L=512, Z=128, H=4, C=32.
// Pipeline: prep -> proj(LN fused) -> att(split-K) -> softmax -> o(gate fused) -> final.
// All GEMMs: mfma_f32_16x16x32_bf16, bf16 operands / fp32 accumulate.
// R1: k_proj one block per mtile loops all 5 ntiles; B frags from L2-resident Wt.
// R2: k_proj holds z in registers across stats+normalize (kills 2nd 134MB HBM pass);
//     epilogue i-outer/j-inner so each 128B proj line completes in one wave burst
//     (reduces partial-line eviction churn seen as FETCH/WRITE amplification).

#define LL 512
#define ZD 128
#define NROWS (LL*LL)
#define ATT_SCALE (1.0f/128.0f)   // (1/sqrt(32))/sqrt(512)
#define NSPLIT 8

typedef __attribute__((ext_vector_type(4))) float f32x4;
typedef __attribute__((ext_vector_type(8))) short short8;
typedef __attribute__((ext_vector_type(8))) unsigned short u16x8;

__device__ __forceinline__ unsigned short f2bf(float f){
  union { float f; unsigned u; } v; v.f = f;
  unsigned r = (v.u + 0x7FFFu + ((v.u >> 16) & 1u)) >> 16;
  return (unsigned short)r;
}
__device__ __forceinline__ float bf2f(unsigned short h){
  union { float f; unsigned u; } v; v.u = ((unsigned)h) << 16;
  return v.f;
}

// ---------------------------------------------------------------- prep
// Wt[n][k] bf16, n: 0-127 qw | 128-255 kw | 256-383 vw | 384-511 gw | 512-515 bw.
// Ot[d][k] = ow[k][d]. biasv[n] packed biases.
__global__ void k_prep(const float* __restrict__ qw, const float* __restrict__ kw,
                       const float* __restrict__ vw, const float* __restrict__ gw,
                       const float* __restrict__ bw,
                       const float* __restrict__ qb, const float* __restrict__ kb,
                       const float* __restrict__ vb, const float* __restrict__ gb,
                       const float* __restrict__ bb,
                       const float* __restrict__ ow,
                       unsigned short* __restrict__ Wt, unsigned short* __restrict__ Ot,
                       float* __restrict__ biasv){
  int n = blockIdx.x;
  int k = threadIdx.x;
  if (n < 516){
    float v;
    if (n < 128)      v = qw[k*128 + n];
    else if (n < 256) v = kw[k*128 + (n-128)];
    else if (n < 384) v = vw[k*128 + (n-256)];
    else if (n < 512) v = gw[k*128 + (n-384)];
    else              v = bw[k*4   + (n-512)];
    Wt[n*ZD + k] = f2bf(v);
    if (k == 0){
      float bvv;
      if (n < 128)      bvv = qb[n];
      else if (n < 256) bvv = kb[n-128];
      else if (n < 384) bvv = vb[n-256];
      else if (n < 512) bvv = gb[n-384];
      else              bvv = bb[n-512];
      biasv[n] = bvv;
    }
  } else {
    int d = n - 516;
    Ot[d*ZD + k] = f2bf(ow[k*ZD + d]);
  }
}

// ---------------------------------------------------------------- proj (LN fused)
// grid 2048 mtiles. Each block: load its 128x128 z tile into REGISTERS once
// (zv[16] float4, statically indexed), LN stats + normalize from regs -> As.
// Then loop the 5 ntiles with B fragments loaded directly from L2-resident Wt.
// MFMA operands SWAPPED (mfma(b,a,acc)) => lane regs span 4 consecutive out-cols.
// Epilogue: i-outer/j-inner, hoisted bias regs -> each 128B line finishes in a
// single wave burst of packed ushort4 stores.
__launch_bounds__(256, 3)
__global__ void k_proj(const float* __restrict__ z,
                       const float* __restrict__ ln_g, const float* __restrict__ ln_b,
                       const unsigned short* __restrict__ Wt,
                       const float* __restrict__ biasv,
                       unsigned short* __restrict__ proj,
                       float* __restrict__ biasz){
  const int P = 136;
  __shared__ unsigned short As[128*136];
  __shared__ float lng[128], lnb[128];
  __shared__ float lbias[640];
  int t = threadIdx.x;
  long mbase = (long)blockIdx.x * 128;
  if (t < 128){ lng[t] = ln_g[t]; lnb[t] = ln_b[t]; }
  if (t < 160) *(float4*)&lbias[t*4] = *(const float4*)&biasv[t*4];
  {
    int row = t >> 1, half = t & 1;
    const float4* zr = (const float4*)(z + (mbase + row)*ZD + half*64);
    float4 zv[16];
    float s1 = 0.f, s2 = 0.f;
#pragma unroll
    for (int i = 0; i < 16; i++){
      zv[i] = zr[i];
      s1 += zv[i].x + zv[i].y + zv[i].z + zv[i].w;
      s2 += zv[i].x*zv[i].x + zv[i].y*zv[i].y + zv[i].z*zv[i].z + zv[i].w*zv[i].w;
    }
    s1 += __shfl_xor(s1, 1);
    s2 += __shfl_xor(s2, 1);
    float mu = s1 * (1.f/128.f);
    float rs = rsqrtf(s2*(1.f/128.f) - mu*mu + 1e-5f);
    __syncthreads();   // lng/lnb/lbias visible
#pragma unroll
    for (int i = 0; i < 16; i++){
      int c0 = half*64 + i*4;
      ushort4 pk;
      pk.x = f2bf((zv[i].x - mu)*rs*lng[c0+0] + lnb[c0+0]);
      pk.y = f2bf((zv[i].y - mu)*rs*lng[c0+1] + lnb[c0+1]);
      pk.z = f2bf((zv[i].z - mu)*rs*lng[c0+2] + lnb[c0+2]);
      pk.w = f2bf((zv[i].w - mu)*rs*lng[c0+3] + lnb[c0+3]);
      *(ushort4*)&As[row*P + c0] = pk;
    }
  }
  __syncthreads();
  int w = t >> 6, tl = t & 63;
  int m0 = (w & 1)*64, n0 = (w >> 1)*64;
  int lr = tl & 15, quad = tl >> 4;
  for (int nt = 0; nt < 5; nt++){
    f32x4 acc[4][4];
    for (int i=0;i<4;i++) for (int j=0;j<4;j++) acc[i][j] = f32x4{0.f,0.f,0.f,0.f};
    for (int kk = 0; kk < 4; kk++){
      short8 a[4], bq[4];
      for (int i=0;i<4;i++) a[i] = *(const short8*)&As[(m0 + i*16 + lr)*P + kk*32 + quad*8];
      const unsigned short* wp = Wt + ((long)nt*128 + n0 + lr)*ZD + kk*32 + quad*8;
      for (int j=0;j<4;j++) bq[j] = *(const short8*)(wp + (long)j*16*ZD);
      for (int i=0;i<4;i++) for (int j=0;j<4;j++)
        acc[i][j] = __builtin_amdgcn_mfma_f32_16x16x32_bf16(bq[j], a[i], acc[i][j], 0,0,0);
    }
    // swapped layout: lane holds rows (m0+i*16+lr), 4 consecutive cols (n0+j*16+quad*4 + 0..3)
    if (nt < 4){
      float4 bd[4];
#pragma unroll
      for (int j=0;j<4;j++) bd[j] = *(const float4*)&lbias[nt*128 + n0 + j*16 + quad*4];
#pragma unroll
      for (int i=0;i<4;i++){
        long grow = mbase + m0 + i*16 + lr;
#pragma unroll
        for (int j=0;j<4;j++){
          int nc0 = n0 + j*16 + quad*4;
          ushort4 pk;
          pk.x = f2bf(acc[i][j][0] + bd[j].x);
          pk.y = f2bf(acc[i][j][1] + bd[j].y);
          pk.z = f2bf(acc[i][j][2] + bd[j].z);
          pk.w = f2bf(acc[i][j][3] + bd[j].w);
          *(ushort4*)&proj[grow*512 + nt*128 + nc0] = pk;
        }
      }
    } else if (n0 == 0 && quad == 0){
      float4 bd = *(const float4*)&lbias[512];
#pragma unroll
      for (int i=0;i<4;i++){
        long grow = mbase + m0 + i*16 + lr;
        float4 o;
        o.x = acc[i][0][0] + bd.x;
        o.y = acc[i][0][1] + bd.y;
        o.z = acc[i][0][2] + bd.z;
        o.w = acc[i][0][3] + bd.w;
        *(float4*)&biasz[grow*4] = o;
      }
    }
  }
}

// ---------------------------------------------------------------- att (split-K)
// att_part[s][h][l][k'] = sum over b in split s of q[b,l,h,:].k[b,k',h,:]
// grid (kt 4, lt 4, split*4+h 32). K-loop: 64 b-iters, BK = 32 (the c dim).
__launch_bounds__(256, 2)
__global__ void k_att(const unsigned short* __restrict__ proj,
                      float* __restrict__ partial){
  const int P = 40;
  __shared__ unsigned short As[128*40];
  __shared__ unsigned short Bs[128*40];
  int t = threadIdx.x;
  int ktb = blockIdx.x * 128, ltb = blockIdx.y * 128;
  int split = blockIdx.z >> 2, h = blockIdx.z & 3;
  int w = t >> 6, tl = t & 63;
  int m0 = (w & 1)*64, n0 = (w >> 1)*64;
  int lr = tl & 15, quad = tl >> 4;
  int srow = t >> 1, shalf = t & 1;
  f32x4 acc[4][4];
  for (int i=0;i<4;i++) for (int j=0;j<4;j++) acc[i][j] = f32x4{0.f,0.f,0.f,0.f};
  for (int it = 0; it < 64; it++){
    int b = split*64 + it;
    long abase = ((long)b*LL + ltb + srow)*512 +       h*32 + shalf*16;
    long bbase = ((long)b*LL + ktb + srow)*512 + 128 + h*32 + shalf*16;
    u16x8 av0 = *(const u16x8*)&proj[abase];
    u16x8 av1 = *(const u16x8*)&proj[abase + 8];
    u16x8 bv0 = *(const u16x8*)&proj[bbase];
    u16x8 bv1 = *(const u16x8*)&proj[bbase + 8];
    __syncthreads();
    *(u16x8*)&As[srow*P + shalf*16]     = av0;
    *(u16x8*)&As[srow*P + shalf*16 + 8] = av1;
    *(u16x8*)&Bs[srow*P + shalf*16]     = bv0;
    *(u16x8*)&Bs[srow*P + shalf*16 + 8] = bv1;
    __syncthreads();
    short8 a[4], bq[4];
    for (int i=0;i<4;i++) a[i]  = *(const short8*)&As[(m0 + i*16 + lr)*P + quad*8];
    for (int i=0;i<4;i++) bq[i] = *(const short8*)&Bs[(n0 + i*16 + lr)*P + quad*8];
    for (int i=0;i<4;i++) for (int j=0;j<4;j++)
      acc[i][j] = __builtin_amdgcn_mfma_f32_16x16x32_bf16(a[i], bq[j], acc[i][j], 0,0,0);
  }
  long obase = (((long)(split*4 + h)*LL) + ltb)*512 + ktb;
  for (int i=0;i<4;i++) for (int j=0;j<4;j++){
    int ncol = n0 + j*16 + lr;
    for (int r=0;r<4;r++){
      int mrow = m0 + i*16 + quad*4 + r;
      partial[obase + (long)mrow*512 + ncol] = acc[i][j][r];
    }
  }
}

// ---------------------------------------------------------------- softmax
// grid 2048 = (h,l). sum splits, scale, +bias, softmax over k (512), write bf16.
__global__ void k_soft(const float* __restrict__ partial,
                       const float* __restrict__ biasz,
                       unsigned short* __restrict__ attb){
  int bx = blockIdx.x;
  int h = bx >> 9, l = bx & 511;
  int t = threadIdx.x;
  int k1 = t, k2 = t + 256;
  float v1 = 0.f, v2 = 0.f;
  for (int s = 0; s < NSPLIT; s++){
    long base = (((long)(s*4 + h)*LL) + l)*512;
    v1 += partial[base + k1];
    v2 += partial[base + k2];
  }
  v1 = v1*ATT_SCALE + biasz[((long)l*512 + k1)*4 + h];
  v2 = v2*ATT_SCALE + biasz[((long)l*512 + k2)*4 + h];
  __shared__ float red[4];
  int w = t >> 6, tl = t & 63;
  float mx = fmaxf(v1, v2);
  for (int o = 32; o > 0; o >>= 1) mx = fmaxf(mx, __shfl_xor(mx, o));
  if (tl == 0) red[w] = mx;
  __syncthreads();
  mx = fmaxf(fmaxf(red[0], red[1]), fmaxf(red[2], red[3]));
  __syncthreads();
  float e1 = __expf(v1 - mx), e2 = __expf(v2 - mx);
  float sm = e1 + e2;
  for (int o = 32; o > 0; o >>= 1) sm += __shfl_xor(sm, o);
  if (tl == 0) red[w] = sm;
  __syncthreads();
  sm = red[0] + red[1] + red[2] + red[3];
  float inv = 1.f / sm;
  long ob = ((long)h*LL + l)*512;
  attb[ob + k1] = f2bf(e1*inv);
  attb[ob + k2] = f2bf(e2*inv);
}

// ---------------------------------------------------------------- o GEMM + gate
// grid (lt 4, b 512). wave w = head w: [128 l] x [32 c], K-loop over k' (BK=32).
// B tile (v) transposed k,c -> c,k in LDS. Epilogue: x = sigmoid(g) * o -> bf16.
__launch_bounds__(256, 2)
__global__ void k_o(const unsigned short* __restrict__ attb,
                    const unsigned short* __restrict__ proj,
                    unsigned short* __restrict__ xbuf){
  const int P = 40;
  __shared__ unsigned short As[4*128*40];
  __shared__ unsigned short Bs[4*32*40];
  int t = threadIdx.x;
  int ltb = blockIdx.x * 128;
  int b   = blockIdx.y;
  int w = t >> 6, tl = t & 63;
  int lr = tl & 15, quad = tl >> 4;
  f32x4 acc[8][2];
  for (int i=0;i<8;i++) for (int j=0;j<2;j++) acc[i][j] = f32x4{0.f,0.f,0.f,0.f};
  for (int it = 0; it < 16; it++){
    int kb = it*32;
    long a0 = (((long)w*LL) + ltb + tl)*512 + kb;
    long a1 = a0 + 64L*512;
    u16x8 r0[4], r1[4];
    for (int i=0;i<4;i++) r0[i] = *(const u16x8*)&attb[a0 + i*8];
    for (int i=0;i<4;i++) r1[i] = *(const u16x8*)&attb[a1 + i*8];
    int kp = tl >> 1, hc2 = tl & 1;
    long vbs = ((long)b*LL + kb + kp)*512 + 256 + w*32 + hc2*16;
    u16x8 v0 = *(const u16x8*)&proj[vbs];
    u16x8 v1 = *(const u16x8*)&proj[vbs + 8];
    __syncthreads();
    for (int i=0;i<4;i++) *(u16x8*)&As[(w*128 + tl)*P + i*8]      = r0[i];
    for (int i=0;i<4;i++) *(u16x8*)&As[(w*128 + tl + 64)*P + i*8] = r1[i];
    for (int j=0;j<8;j++){
      Bs[(w*32 + hc2*16 + j    )*P + kp] = v0[j];
      Bs[(w*32 + hc2*16 + 8 + j)*P + kp] = v1[j];
    }
    __syncthreads();
    short8 a[8], bq[2];
    for (int i=0;i<8;i++) a[i]  = *(const short8*)&As[(w*128 + i*16 + lr)*P + quad*8];
    for (int j=0;j<2;j++) bq[j] = *(const short8*)&Bs[(w*32  + j*16 + lr)*P + quad*8];
    for (int i=0;i<8;i++) for (int j=0;j<2;j++)
      acc[i][j] = __builtin_amdgcn_mfma_f32_16x16x32_bf16(a[i], bq[j], acc[i][j], 0,0,0);
  }
  for (int i=0;i<8;i++) for (int j=0;j<2;j++) for (int r=0;r<4;r++){
    int l = i*16 + quad*4 + r;
    int c = j*16 + lr;
    long grow = (long)b*LL + ltb + l;
    float gv = bf2f(proj[grow*512 + 384 + w*32 + c]);
    float sg = 1.f / (1.f + __expf(-gv));
    xbuf[grow*128 + w*32 + c] = f2bf(acc[i][j][r] * sg);
  }
}

// ---------------------------------------------------------------- final projection
// out[row][d] = x[row][:] @ ow + ob, fp32 out. grid 2048 mtiles, K=128 one-shot.
__launch_bounds__(256, 2)
__global__ void k_fin(const unsigned short* __restrict__ xbuf,
                      const unsigned short* __restrict__ Ot,
                      const float* __restrict__ ob,
                      float* __restrict__ out){
  const int P = 136;
  __shared__ unsigned short As[128*136];
  __shared__ unsigned short Bs[128*136];
  int t = threadIdx.x;
  long mbase = (long)blockIdx.x * 128;
  {
    int row = t >> 1, half = t & 1;
    const u16x8* src = (const u16x8*)(xbuf + (mbase + row)*128 + half*64);
    u16x8* dst = (u16x8*)&As[row*P + half*64];
    for (int i=0;i<8;i++) dst[i] = src[i];
    const u16x8* wsrc = (const u16x8*)(Ot + row*128 + half*64);
    u16x8* wdst = (u16x8*)&Bs[row*P + half*64];
    for (int i=0;i<8;i++) wdst[i] = wsrc[i];
  }
  __syncthreads();
  int w = t >> 6, tl = t & 63;
  int m0 = (w & 1)*64, n0 = (w >> 1)*64;
  int lr = tl & 15, quad = tl >> 4;
  f32x4 acc[4][4];
  for (int i=0;i<4;i++) for (int j=0;j<4;j++) acc[i][j] = f32x4{0.f,0.f,0.f,0.f};
  for (int kk = 0; kk < 4; kk++){
    short8 a[4], bq[4];
    for (int i=0;i<4;i++) a[i]  = *(const short8*)&As[(m0 + i*16 + lr)*P + kk*32 + quad*8];
    for (int i=0;i<4;i++) bq[i] = *(const short8*)&Bs[(n0 + i*16 + lr)*P + kk*32 + quad*8];
    for (int i=0;i<4;i++) for (int j=0;j<4;j++)
      acc[i][j] = __builtin_amdgcn_mfma_f32_16x16x32_bf16(a[i], bq[j], acc[i][j], 0,0,0);
  }
  for (int i=0;i<4;i++) for (int j=0;j<4;j++){
    int ncol = n0 + j*16 + lr;
    float bv = ob[ncol];
    for (int r=0;r<4;r++){
      int mrow = m0 + i*16 + quad*4 + r;
      out[(mbase + mrow)*128 + ncol] = acc[i][j][r] + bv;
    }
  }
}

// ---------------------------------------------------------------- launch
extern "C" void kernel_launch(void* const* d_in, const int* in_sizes, int n_in,
                              void* d_out, int out_size, void* d_ws, size_t ws_size,
                              hipStream_t stream){
  (void)in_sizes; (void)n_in; (void)out_size; (void)ws_size;
  const float* z    = (const float*)d_in[0];
  const float* ln_g = (const float*)d_in[1];
  const float* ln_b = (const float*)d_in[2];
  const float* qw   = (const float*)d_in[3];
  const float* qb   = (const float*)d_in[4];
  const float* kw   = (const float*)d_in[5];
  const float* kb   = (const float*)d_in[6];
  const float* vw   = (const float*)d_in[7];
  const float* vb   = (const float*)d_in[8];
  const float* bw   = (const float*)d_in[9];
  const float* bb   = (const float*)d_in[10];
  const float* gw   = (const float*)d_in[11];
  const float* gb   = (const float*)d_in[12];
  const float* ow   = (const float*)d_in[13];
  const float* ob   = (const float*)d_in[14];
  float* out = (float*)d_out;

  // ws layout (~323 MB):
  //   [0,       163840)  Wt   640x128 bf16 (rows 516.. left as poison; never stored from)
  //   [163840,  196608)  Ot   128x128 bf16
  //   [196608,  199168)  biasv 640 fp32 (516 used)
  //   [262144,  +256MB)  proj 262144x512 bf16 (q|k|v|g)
  //   [Xreg,    +64MB )  union: {partial 32MB fp32 ; biasz 4MB fp32} then xbuf 64MB bf16
  //   [Xreg+64MB,+2MB )  attb 4x512x512 bf16
  char* wsp = (char*)d_ws;
  unsigned short* Wt    = (unsigned short*)(wsp);
  unsigned short* Ot    = (unsigned short*)(wsp + 163840);
  float*          biasv = (float*)(wsp + 196608);
  unsigned short* proj  = (unsigned short*)(wsp + 262144);
  char* xreg = wsp + 262144 + 268435456L;
  float*          partial = (float*)xreg;
  float*          biasz   = (float*)(xreg + 33554432L);
  unsigned short* xbuf    = (unsigned short*)xreg;
  unsigned short* attb    = (unsigned short*)(xreg + 67108864L);

  k_prep<<<644, 128, 0, stream>>>(qw,kw,vw,gw,bw,qb,kb,vb,gb,bb,ow,Wt,Ot,biasv);
  k_proj<<<2048, 256, 0, stream>>>(z, ln_g, ln_b, Wt, biasv, proj, biasz);
  k_att<<<dim3(4,4,32), 256, 0, stream>>>(proj, partial);
  k_soft<<<2048, 256, 0, stream>>>(partial, biasz, attb);
  k_o<<<dim3(4,512), 256, 0, stream>>>(attb, proj, xbuf);
  k_fin<<<2048, 256, 0, stream>>>(xbuf, Ot, ob, out);
}